// Round 16
// baseline (60.977 us; speedup 1.0000x reference)
//
#include <hip/hip_runtime.h>
#include <hip/hip_bf16.h>
#include <cmath>

typedef __attribute__((ext_vector_type(8))) short short8;
typedef __attribute__((ext_vector_type(4))) float f32x4;
typedef __attribute__((ext_vector_type(4))) int int4v;

#define B_SZ 64
#define T_SZ 8192
#define D_SZ 128
#define U_SZ 128
#define NW 8                      /* waves per block */
#define T_TILE 128                /* rows per block-tile: NW waves x 16 rows */
#define GRID_P 256
#define TILES_PER_BLK 16          /* 256 blocks x 16 tiles x 128 rows = 64*8192 */
#define BLKS_PER_B 4              /* GRID_P / B_SZ */
#define P_STRIDE 132              /* c[128] + m + s, padded */
#define WT_LD 136                 /* bf16 row stride: 272B */
#define TANH_SCALE 2.8853900817779268f   /* 2*log2(e) */
#define DEFER_THR 8.0f            /* defer-max rescale threshold (T13) */

__device__ __forceinline__ unsigned short f2bf(float f) {
  unsigned int u = __builtin_bit_cast(unsigned int, f);
  u += 0x7fffu + ((u >> 16) & 1u);
  return (unsigned short)(u >> 16);
}

__device__ __forceinline__ float bf2f(unsigned short s) {
  return __builtin_bit_cast(float, (unsigned int)s << 16);
}

// DPP row-reduce within each 16-lane row (VALU pipe only).
template<int CTRL>
__device__ __forceinline__ float dpp_add(float v) {
  int t = __builtin_amdgcn_update_dpp(0, __builtin_bit_cast(int, v),
                                      CTRL, 0xf, 0xf, true);
  return v + __builtin_bit_cast(float, t);
}
__device__ __forceinline__ float row_reduce16(float v) {
  v = dpp_add<0x118>(v);  // row_shr:8
  v = dpp_add<0x114>(v);  // row_shr:4
  v = dpp_add<0x112>(v);  // row_shr:2
  v = dpp_add<0x111>(v);  // row_shr:1
  return v;               // lane lr==15 of each 16-lane row holds the sum
}

// fp32x8 -> bf16x8 via hardware packed converts (RNE). VOP3, no trans hazard.
__device__ __forceinline__ void cvt_tile(const f32x4 pf[8], short8 afrag[4]) {
#pragma unroll
  for (int kt = 0; kt < 4; ++kt) {
    f32x4 f0 = pf[kt * 2], f1 = pf[kt * 2 + 1];
    int w0, w1, w2, w3;
    asm("v_cvt_pk_bf16_f32 %0, %1, %2" : "=v"(w0) : "v"(f0[0]), "v"(f0[1]));
    asm("v_cvt_pk_bf16_f32 %0, %1, %2" : "=v"(w1) : "v"(f0[2]), "v"(f0[3]));
    asm("v_cvt_pk_bf16_f32 %0, %1, %2" : "=v"(w2) : "v"(f1[0]), "v"(f1[1]));
    asm("v_cvt_pk_bf16_f32 %0, %1, %2" : "=v"(w3) : "v"(f1[2]), "v"(f1[3]));
    int4v w = {w0, w1, w2, w3};
    afrag[kt] = __builtin_bit_cast(short8, w);
  }
}

// ---------------------------------------------------------------------------
// Kernel 0: W [d][u] fp32 -> Wt [u][d] bf16 PRESCALED by 2*log2e (once, tiny)
// ---------------------------------------------------------------------------
__global__ void k_prep(const float* __restrict__ wk, unsigned short* __restrict__ wt) {
  int i = blockIdx.x * 256 + threadIdx.x;
  if (i < D_SZ * U_SZ) {
    int d = i >> 7, u = i & 127;
    wt[u * D_SZ + d] = f2bf(wk[i] * TANH_SCALE);
  }
}

// ---------------------------------------------------------------------------
// Kernel 1: R14 geometry (256 blocks x 8 waves x 16 tiles of 128 rows:
// 256 x 1MB sequential HBM streams, waves/CU unchanged) with the R14 NaN
// suspect fixed: tanh's 2^x now uses exp2f() (compiler-lowered v_exp_f32
// WITH post-RA trans-hazard handling) instead of raw inline asm, whose
// required wait-states the hazard recognizer cannot insert around opaque
// asm blocks. All else identical to the passing R13 body.
// ---------------------------------------------------------------------------
__global__ __launch_bounds__(512) void k_partial(
    const float* __restrict__ x, const unsigned short* __restrict__ wt_g,
    const float* __restrict__ wb, const float* __restrict__ v,
    const float* __restrict__ vb, float* __restrict__ pbuf)
{
  __shared__ unsigned short wt[U_SZ][WT_LD];  // 34816 B
  __shared__ float wb_s[U_SZ], v_s[U_SZ];     // 1 KB
  __shared__ float logits[NW][16];            // wave-private slices
  __shared__ float fin[NW][D_SZ];             // final merge buffers (4 KB)
  __shared__ float fm[NW], fs[NW];

  const int tid  = threadIdx.x;
  const int bidx = blockIdx.x;

  for (int i = tid; i < U_SZ * 16; i += 512) {
    int row = i >> 4, c16 = i & 15;
    uint4 val = ((const uint4*)wt_g)[i];
    *(uint4*)&wt[row][c16 * 8] = val;
  }
  if (tid < U_SZ) { wb_s[tid] = wb[tid] * TANH_SCALE; v_s[tid] = v[tid]; }
  __syncthreads();

  const int w  = tid >> 6;          // wave 0..7 -> rows w*16..w*16+15 of tile
  const int l  = tid & 63;
  const int lr = l & 15;            // A row within the wave's 16-row subtile
  const int lh = l >> 4;            // k-subchunk / D-col group
  const float vbias = vb[0];

  // loop-invariant: sum of v over this lane's u-column set
  float vsum = 0.0f;
#pragma unroll
  for (int ut = 0; ut < 8; ++ut) vsum += v_s[ut * 16 + lr];

  const int b        = bidx >> 2;                          // /BLKS_PER_B
  const int row0     = (bidx & (BLKS_PER_B - 1)) * (TILES_PER_BLK * T_TILE);
  const float* xbase = x + ((size_t)b * T_SZ + row0 + w * 16 + lr) * D_SZ + lh * 8;

  f32x4 pf[8];
#pragma unroll
  for (int kt = 0; kt < 4; ++kt) {
    pf[kt * 2]     = *(const f32x4*)(xbase + kt * 32);
    pf[kt * 2 + 1] = *(const f32x4*)(xbase + kt * 32 + 4);
  }
  short8 afrag[4];
  cvt_tile(pf, afrag);

  float m_run = -3.0e38f, s_run = 0.0f;
  float rc[4][8];
#pragma unroll
  for (int kt = 0; kt < 4; ++kt)
#pragma unroll
    for (int j = 0; j < 8; ++j) rc[kt][j] = 0.0f;

  for (int it = 0; it < TILES_PER_BLK; ++it) {
    // issue next tile's loads; pinned at the top by sched_barrier below
    if (it + 1 < TILES_PER_BLK) {
      const float* p = xbase + (size_t)(it + 1) * T_TILE * D_SZ;
#pragma unroll
      for (int kt = 0; kt < 4; ++kt) {
        pf[kt * 2]     = *(const f32x4*)(p + kt * 32);
        pf[kt * 2 + 1] = *(const f32x4*)(p + kt * 32 + 4);
      }
      __builtin_amdgcn_sched_barrier(0);  // loads may not sink below this
    }

    // ---- logits: 8 u-tiles x 4 k-tiles MFMA; bias in acc init;
    //      lg accumulates sum(v*rcp(2^acc + 1)) ----
    float lg[4] = {0.f, 0.f, 0.f, 0.f};
#pragma unroll
    for (int ut = 0; ut < 8; ++ut) {
      const float wbv = wb_s[ut * 16 + lr];
      f32x4 acc = {wbv, wbv, wbv, wbv};
#pragma unroll
      for (int kt = 0; kt < 4; ++kt) {
        short8 bfrag = *(const short8*)&wt[ut * 16 + lr][kt * 32 + lh * 8];
        acc = __builtin_amdgcn_mfma_f32_16x16x32_bf16(afrag[kt], bfrag, acc, 0, 0, 0);
      }
      const float vv = v_s[ut * 16 + lr];
#pragma unroll
      for (int r = 0; r < 4; ++r)
        lg[r] = fmaf(vv, __builtin_amdgcn_rcpf(exp2f(acc[r]) + 1.0f), lg[r]);
    }
#pragma unroll
    for (int r = 0; r < 4; ++r) {
      lg[r] = row_reduce16(fmaf(-2.0f, lg[r], vsum));
    }
    if (lr == 15) {
#pragma unroll
      for (int r = 0; r < 4; ++r)
        logits[w][lh * 4 + r] = lg[r] + vbias;   // wave-private: no barrier
    }

    // ---- per-wave online softmax with defer-max (T13) ----
    float lv = logits[w][lr];         // same-wave LDS RAW: lgkmcnt only
    float mx = lv;
#pragma unroll
    for (int k = 1; k <= 8; k <<= 1) mx = fmaxf(mx, __shfl_xor(mx, k, 64));
    if (mx > m_run + DEFER_THR) {     // wave-uniform branch; rare after tile 0
      const float e_old = __expf(m_run - mx);
      s_run *= e_old;
#pragma unroll
      for (int kt = 0; kt < 4; ++kt)
#pragma unroll
        for (int j = 0; j < 8; ++j) rc[kt][j] *= e_old;
      m_run = mx;
    }
    const float pr = __expf(lv - m_run);        // bounded by e^DEFER_THR
    float ss = pr;
#pragma unroll
    for (int k = 1; k <= 8; k <<= 1) ss += __shfl_xor(ss, k, 64);
    s_run += ss;

    // ---- per-lane context accumulate: bf2f + fmac only ----
#pragma unroll
    for (int kt = 0; kt < 4; ++kt) {
#pragma unroll
      for (int j = 0; j < 8; ++j) {
        rc[kt][j] = fmaf(pr, bf2f((unsigned short)afrag[kt][j]), rc[kt][j]);
      }
    }

    // ---- scheduling fence only (no block sync): cvt may not hoist up ----
    __builtin_amdgcn_sched_barrier(0);
    if (it + 1 < TILES_PER_BLK) cvt_tile(pf, afrag);
  }

  // ---- one-time 16-row reduce + cross-wave merge (8 waves) ----
  if (l == 0) { fm[w] = m_run; fs[w] = s_run; }
  __syncthreads();
  float m_blk = fm[0];
#pragma unroll
  for (int i = 1; i < NW; ++i) m_blk = fmaxf(m_blk, fm[i]);
  const float e_w = __expf(m_run - m_blk);
#pragma unroll
  for (int kt = 0; kt < 4; ++kt) {
    float cs[8];
#pragma unroll
    for (int j = 0; j < 8; ++j) cs[j] = row_reduce16(rc[kt][j]);
    if (lr == 15) {
      f32x4 v0 = {cs[0] * e_w, cs[1] * e_w, cs[2] * e_w, cs[3] * e_w};
      f32x4 v1 = {cs[4] * e_w, cs[5] * e_w, cs[6] * e_w, cs[7] * e_w};
      *(f32x4*)&fin[w][kt * 32 + lh * 8]     = v0;
      *(f32x4*)&fin[w][kt * 32 + lh * 8 + 4] = v1;
    }
  }
  __syncthreads();

  float* pb = pbuf + (size_t)bidx * P_STRIDE;
  if (tid < 128) {
    float cs = 0.0f;
#pragma unroll
    for (int i = 0; i < NW; ++i) cs += fin[i][tid];
    pb[tid] = cs;
  } else if (tid == 128) {
    pb[128] = m_blk;
  } else if (tid == 129) {
    float sb = 0.0f;
#pragma unroll
    for (int i = 0; i < NW; ++i) sb += fs[i] * __expf(fm[i] - m_blk);
    pb[129] = sb;
  }
}

// ---------------------------------------------------------------------------
// Kernel 2: combine 4 block-partials per batch with global softmax rescale
// ---------------------------------------------------------------------------
__global__ __launch_bounds__(128) void k_combine(const float* __restrict__ pbuf,
                                                 float* __restrict__ out)
{
  const int b = blockIdx.x, tid = threadIdx.x;
  __shared__ float sm[BLKS_PER_B], sden[BLKS_PER_B];
  const float* base = pbuf + (size_t)b * BLKS_PER_B * P_STRIDE;

  if (tid < BLKS_PER_B) {
    sm[tid]   = base[tid * P_STRIDE + 128];
    sden[tid] = base[tid * P_STRIDE + 129];
  }
  __syncthreads();

  float mx = -3.0e38f;
#pragma unroll
  for (int i = 0; i < BLKS_PER_B; ++i) mx = fmaxf(mx, sm[i]);
  float den = 0.0f, c = 0.0f;
#pragma unroll
  for (int i = 0; i < BLKS_PER_B; ++i) {
    float e = __expf(sm[i] - mx);
    den += sden[i] * e;
    c = fmaf(base[(size_t)i * P_STRIDE + tid], e, c);
  }
  out[b * D_SZ + tid] = c / den;
}

// ---------------------------------------------------------------------------
extern "C" void kernel_launch(void* const* d_in, const int* in_sizes, int n_in,
                              void* d_out, int out_size, void* d_ws, size_t ws_size,
                              hipStream_t stream) {
  const float* x  = (const float*)d_in[0];  // [B,T,D]
  const float* wk = (const float*)d_in[1];  // [D,U]
  const float* wb = (const float*)d_in[2];  // [U]
  const float* vk = (const float*)d_in[3];  // [U,1]
  const float* vb = (const float*)d_in[4];  // [1]
  float* out = (float*)d_out;               // [B,D]

  unsigned short* wt = (unsigned short*)d_ws;       // 32 KB bf16 Wt[u][d] (prescaled)
  float* pbuf = (float*)((char*)d_ws + 32768);      // 256 * 132 floats

  k_prep<<<64, 256, 0, stream>>>(wk, wt);
  k_partial<<<GRID_P, 512, 0, stream>>>(x, wt, wb, vk, vb, pbuf);
  k_combine<<<B_SZ, 128, 0, stream>>>(pbuf, out);
}